// Round 1
// baseline (1244.609 us; speedup 1.0000x reference)
//
#include <hip/hip_runtime.h>

// ---------------- types & helpers ----------------
typedef __attribute__((ext_vector_type(8))) short sh8;   // 8 bf16 (4 VGPRs)
typedef __attribute__((ext_vector_type(4))) float f32x4; // MFMA C/D

#define MFMA(a, b, c) __builtin_amdgcn_mfma_f32_16x16x32_bf16(a, b, c, 0, 0, 0)

__device__ __forceinline__ short f2bf(float f) {
    unsigned u = __builtin_bit_cast(unsigned, f);
    u += 0x7fffu + ((u >> 16) & 1u);   // RNE
    return (short)(u >> 16);
}

// Problem constants
#define B_   16384
#define NW   256
#define NT   49      // tokens per window
#define DIM  128
#define HEADS 4
#define HD   32
#define SCALE 0.17677669529663687f   // 32^-0.5

// ws layout (bytes)
#define V_BYTES     205520896u           // [B_][H][49][32] bf16
#define AMASK_OFF   205520896u           // [H][NW][64][64] fp32 = 16,777,216
#define QW_OFF      222298112u           // [384][128] bf16 = 98,304
#define PW_OFF      222396416u           // [128][128] bf16 = 32,768
// total: 222,429,184 bytes

// ---------------- kernel 1: precompute ----------------
// amask[h][wi][r][c] = bias(h,r,c) + mask(wi,r,c), with -1e30 for c>=49 (softmax pad),
// 0 padding for r>=49 (rows unused but must stay finite).
__global__ __launch_bounds__(256) void wa_prep(
    const float* __restrict__ mask, const float* __restrict__ rpb,
    const int* __restrict__ rpi, const float* __restrict__ qkv_w,
    const float* __restrict__ proj_w, float* __restrict__ amask,
    short* __restrict__ qw, short* __restrict__ pw) {
    int g = blockIdx.x * 256 + threadIdx.x;  // 4,194,304 total
    int c = g & 63, r = (g >> 6) & 63, wi = (g >> 12) & 255, h = g >> 20;
    float v;
    if (c < NT) {
        v = 0.f;
        if (r < NT) {
            int idx = r * NT + c;
            v = rpb[rpi[idx] * HEADS + h] + mask[wi * (NT * NT) + idx];
        }
    } else {
        v = -1e30f;
    }
    amask[g] = v;
    if (g < 384 * 128) qw[g] = f2bf(qkv_w[g]);
    if (g < 128 * 128) pw[g] = f2bf(proj_w[g]);
}

// ---------------- kernel 2: qkv projection GEMM ----------------
// C[t][d] = sum_c x[t][c] * qkv_w[sel*128+d][c] + qkv_b ; M=802816 (=6272*128), K=128.
// sel inner in block id so the 3 sel-blocks sharing an x-tile are dispatch-adjacent (L3 reuse).
// q (scaled) and k are written into d_out (window b's q,k == window b's out bytes), v to ws.
__global__ __launch_bounds__(256, 2) void wa_qkv(
    const float* __restrict__ x, const short* __restrict__ qw,
    const float* __restrict__ qkv_b, short* __restrict__ qk,
    short* __restrict__ vbuf) {
    __shared__ short lA[128 * 152];  // x tile bf16, pad-stride 152 (2-way banks, 16B aligned)
    __shared__ short lB[128 * 152];  // weight tile bf16
    const int tid = threadIdx.x;
    const int bid = blockIdx.x;
    const int sel = bid % 3;
    const int bm  = bid / 3;

    // stage A: x[bm*128 .. +128][0..128) fp32 -> bf16
    {
        const float* xb = x + (size_t)bm * 128 * 128;
#pragma unroll
        for (int i = 0; i < 8; i++) {
            int chunk = i * 256 + tid;            // 2048 chunks of 8 elements
            int row = chunk >> 4, col = (chunk & 15) * 8;
            float4 v0 = *(const float4*)(xb + row * 128 + col);
            float4 v1 = *(const float4*)(xb + row * 128 + col + 4);
            sh8 o;
            o[0] = f2bf(v0.x); o[1] = f2bf(v0.y); o[2] = f2bf(v0.z); o[3] = f2bf(v0.w);
            o[4] = f2bf(v1.x); o[5] = f2bf(v1.y); o[6] = f2bf(v1.z); o[7] = f2bf(v1.w);
            *(sh8*)(&lA[row * 152 + col]) = o;
        }
        const short* wb = qw + sel * 128 * 128;
#pragma unroll
        for (int i = 0; i < 8; i++) {
            int chunk = i * 256 + tid;
            int row = chunk >> 4, col = (chunk & 15) * 8;
            *(sh8*)(&lB[row * 152 + col]) = *(const sh8*)(wb + row * 128 + col);
        }
    }
    __syncthreads();

    const int lane = tid & 63, wid = tid >> 6;
    const int quad = lane >> 4, l15 = lane & 15;
    const int wm = (wid & 1) * 64, wn = (wid >> 1) * 64;

    f32x4 acc[4][4] = {};
#pragma unroll
    for (int ks = 0; ks < 4; ks++) {
        sh8 a[4], b[4];
#pragma unroll
        for (int t = 0; t < 4; t++)
            a[t] = *(const sh8*)(&lA[(wm + t * 16 + l15) * 152 + ks * 32 + quad * 8]);
#pragma unroll
        for (int t = 0; t < 4; t++)
            b[t] = *(const sh8*)(&lB[(wn + t * 16 + l15) * 152 + ks * 32 + quad * 8]);
#pragma unroll
        for (int ti = 0; ti < 4; ti++)
#pragma unroll
            for (int tj = 0; tj < 4; tj++)
                acc[ti][tj] = MFMA(a[ti], b[tj], acc[ti][tj]);
    }

    // epilogue: scatter to q/k (in d_out) or v (ws) as bf16
    float bv[4]; int hh[4], ee[4];
#pragma unroll
    for (int tj = 0; tj < 4; tj++) {
        int n = wn + tj * 16 + l15;
        bv[tj] = qkv_b[sel * 128 + n];
        hh[tj] = n >> 5; ee[tj] = n & 31;
    }
    short* outp = (sel < 2) ? qk : vbuf;
#pragma unroll
    for (int ti = 0; ti < 4; ti++)
#pragma unroll
        for (int reg = 0; reg < 4; reg++) {
            int t = bm * 128 + wm + ti * 16 + quad * 4 + reg;  // C row = quad*4+reg (m89)
            unsigned bwin = (unsigned)t / 49u;
            int nn = t - bwin * 49u;
#pragma unroll
            for (int tj = 0; tj < 4; tj++) {
                float v = acc[ti][tj][reg] + bv[tj];
                if (sel == 0) v *= SCALE;
                size_t dst;
                if (sel < 2)
                    dst = (size_t)bwin * 12544 + (size_t)sel * 6272 +
                          (size_t)(hh[tj] * NT + nn) * HD + ee[tj];
                else
                    dst = (((size_t)bwin * HEADS + hh[tj]) * NT + nn) * HD + ee[tj];
                outp[dst] = f2bf(v);
            }
        }
}

// ---------------- kernel 3: fused attention + proj ----------------
// 1 block / window, wave wid = head. S=QK^T (MFMA) -> +amask -> softmax (shuffle) ->
// P,V^T via LDS -> PV (MFMA) -> ctx to shared LDS -> proj slice (MFMA) -> fp32 out.
// out bytes for window b == q,k bytes for window b: all q,k reads complete before the
// two __syncthreads() that precede the epilogue, so overwrite is safe.
__global__ __launch_bounds__(256, 2) void wa_attn(
    const short* __restrict__ qk, const short* __restrict__ vbuf,
    const float* __restrict__ amask, const short* __restrict__ pw,
    const float* __restrict__ proj_b, float* __restrict__ out) {
    __shared__ short smem[33792];  // [0,22528): P (4x 64x88); [22528,33792): V^T (4x 32x88)
                                   // ctx (64x152=9728) aliases P region after barrier
    const int tid = threadIdx.x, lane = tid & 63, wid = tid >> 6;
    const int quad = lane >> 4, l15 = lane & 15;
    const int b = blockIdx.x, wi = b & 255;
    short* Pl = smem + wid * 5632;
    short* Vl = smem + 22528 + wid * 2816;

    // V transpose into LDS: Vl[e][token], zero-padded tokens 49..63
    {
        const short* vb = vbuf + ((size_t)b * HEADS + wid) * NT * HD;
#pragma unroll
        for (int i = 0; i < 4; i++) {
            int chunk = i * 64 + lane;            // 256 chunks: token=chunk>>2, colc=(chunk&3)*8
            int token = chunk >> 2, colc = (chunk & 3) * 8;
            sh8 v = (sh8)(short)0;
            if (token < NT) v = *(const sh8*)(vb + token * HD + colc);
#pragma unroll
            for (int j = 0; j < 8; j++) Vl[(colc + j) * 88 + token] = v[j];
        }
    }

    // Q,K fragments straight from global (token<49 predicated)
    const short* qb = qk + (size_t)b * 12544 + wid * NT * HD;
    const short* kb = qb + 6272;
    sh8 aq[4], bk[4];
#pragma unroll
    for (int t = 0; t < 4; t++) {
        int tok = t * 16 + l15;
        sh8 z = (sh8)(short)0;
        aq[t] = z; bk[t] = z;
        if (tok < NT) {
            aq[t] = *(const sh8*)(qb + tok * HD + quad * 8);
            bk[t] = *(const sh8*)(kb + tok * HD + quad * 8);
        }
    }
    f32x4 S[4][4] = {};
#pragma unroll
    for (int ti = 0; ti < 4; ti++)
#pragma unroll
        for (int tj = 0; tj < 4; tj++) S[ti][tj] = MFMA(aq[ti], bk[tj], S[ti][tj]);

    // softmax (rows = queries, C row = quad*4+reg; cols spread over lane&15 x tj)
    const float* am = amask + (((size_t)wid * NW + wi) << 12);
    float rinv[4][4];
#pragma unroll
    for (int ti = 0; ti < 4; ti++)
#pragma unroll
        for (int reg = 0; reg < 4; reg++) {
            int row = ti * 16 + quad * 4 + reg;
            float mx = -1e38f;
#pragma unroll
            for (int tj = 0; tj < 4; tj++) {
                float lg = S[ti][tj][reg] + am[row * 64 + tj * 16 + l15];
                S[ti][tj][reg] = lg;
                mx = fmaxf(mx, lg);
            }
#pragma unroll
            for (int d = 1; d < 16; d <<= 1) mx = fmaxf(mx, __shfl_xor(mx, d, 64));
            float sum = 0.f;
#pragma unroll
            for (int tj = 0; tj < 4; tj++) {
                float p = __expf(S[ti][tj][reg] - mx);
                S[ti][tj][reg] = p;
                sum += p;
            }
#pragma unroll
            for (int d = 1; d < 16; d <<= 1) sum += __shfl_xor(sum, d, 64);
            rinv[ti][reg] = 1.f / sum;   // normalization deferred to ctx
        }

    // P (unnormalized) -> LDS bf16
#pragma unroll
    for (int ti = 0; ti < 4; ti++)
#pragma unroll
        for (int reg = 0; reg < 4; reg++) {
            int row = ti * 16 + quad * 4 + reg;
#pragma unroll
            for (int tj = 0; tj < 4; tj++)
                Pl[row * 88 + tj * 16 + l15] = f2bf(S[ti][tj][reg]);
        }

    // PV: A = P[64x64], B = V^T[32x64]
    f32x4 CV[4][2] = {};
#pragma unroll
    for (int ks = 0; ks < 2; ks++) {
        sh8 pa[4], vv[2];
#pragma unroll
        for (int t = 0; t < 4; t++)
            pa[t] = *(const sh8*)(&Pl[(t * 16 + l15) * 88 + ks * 32 + quad * 8]);
#pragma unroll
        for (int t = 0; t < 2; t++)
            vv[t] = *(const sh8*)(&Vl[(t * 16 + l15) * 88 + ks * 32 + quad * 8]);
#pragma unroll
        for (int ti = 0; ti < 4; ti++)
#pragma unroll
            for (int tj = 0; tj < 2; tj++) CV[ti][tj] = MFMA(pa[ti], vv[tj], CV[ti][tj]);
    }

    __syncthreads();  // all waves done reading P/V before ctx aliases P region

    // ctx (normalized) -> shared LDS [64][152], wave writes its head's 32 cols
#pragma unroll
    for (int ti = 0; ti < 4; ti++)
#pragma unroll
        for (int reg = 0; reg < 4; reg++) {
            int row = ti * 16 + quad * 4 + reg;
            float inv = rinv[ti][reg];
#pragma unroll
            for (int tj = 0; tj < 2; tj++)
                smem[row * 152 + wid * 32 + tj * 16 + l15] = f2bf(CV[ti][tj][reg] * inv);
        }
    __syncthreads();

    // proj: wave computes douts [wid*32, wid*32+32), full K=128
    f32x4 O[4][2] = {};
    const short* pwb = pw + (wid * 32) * 128;
#pragma unroll
    for (int ks = 0; ks < 4; ks++) {
        sh8 ca[4], wb2[2];
#pragma unroll
        for (int t = 0; t < 4; t++)
            ca[t] = *(const sh8*)(&smem[(t * 16 + l15) * 152 + ks * 32 + quad * 8]);
#pragma unroll
        for (int t = 0; t < 2; t++)
            wb2[t] = *(const sh8*)(pwb + (t * 16 + l15) * 128 + ks * 32 + quad * 8);
#pragma unroll
        for (int ti = 0; ti < 4; ti++)
#pragma unroll
            for (int tj = 0; tj < 2; tj++) O[ti][tj] = MFMA(ca[ti], wb2[tj], O[ti][tj]);
    }
    float pb[2];
#pragma unroll
    for (int t = 0; t < 2; t++) pb[t] = proj_b[wid * 32 + t * 16 + l15];
    float* ob = out + (size_t)b * NT * DIM;
#pragma unroll
    for (int ti = 0; ti < 4; ti++)
#pragma unroll
        for (int reg = 0; reg < 4; reg++) {
            int row = ti * 16 + quad * 4 + reg;
            if (row < NT) {
#pragma unroll
                for (int tj = 0; tj < 2; tj++)
                    ob[row * DIM + wid * 32 + tj * 16 + l15] = O[ti][tj][reg] + pb[tj];
            }
        }
}

// ---------------- launcher ----------------
extern "C" void kernel_launch(void* const* d_in, const int* in_sizes, int n_in,
                              void* d_out, int out_size, void* d_ws, size_t ws_size,
                              hipStream_t stream) {
    const float* x      = (const float*)d_in[0];
    const float* mask   = (const float*)d_in[1];
    const float* qkv_w  = (const float*)d_in[2];
    const float* qkv_b  = (const float*)d_in[3];
    const float* proj_w = (const float*)d_in[4];
    const float* proj_b = (const float*)d_in[5];
    const float* rpb    = (const float*)d_in[6];
    const int*   rpi    = (const int*)d_in[7];

    char* ws = (char*)d_ws;
    short* vbuf  = (short*)ws;
    float* amask = (float*)(ws + AMASK_OFF);
    short* qw    = (short*)(ws + QW_OFF);
    short* pw    = (short*)(ws + PW_OFF);
    short* qkbuf = (short*)d_out;   // q,k live inside d_out (exact byte overlap per window)
    float* out   = (float*)d_out;

    wa_prep<<<16384, 256, 0, stream>>>(mask, rpb, rpi, qkv_w, proj_w, amask, qw, pw);
    wa_qkv<<<6272 * 3, 256, 0, stream>>>(x, qw, qkv_b, qkbuf, vbuf);
    wa_attn<<<B_, 256, 0, stream>>>(qkbuf, vbuf, amask, pw, proj_b, out);
}